// Round 7
// baseline (188.974 us; speedup 1.0000x reference)
//
#include <hip/hip_runtime.h>
#include <hip/hip_bf16.h>

#define SPIX 1000
#define NCLS 21
#define PP (512*512)          // pixels per image, 2^18
#define NB_IMG 8
#define EPB (NCLS*PP)         // elements per batch in pred (= 21*2^18 f-values)

// scatter geometry: contiguous 32768-wide f-window per block; 2^15 | 2^18 so
// the class row c = f>>18 is CONSTANT within a block.
#define FWIN 32768
#define BLKS_PER_B (EPB / FWIN)   // 168
#define DUMP  1000                // garbage accumulator slot (rows sized 1024)
#define DUMP2 1008                // garbage marker slot for round-2 non-participants
#define KE 8                      // elements per lane per iteration

// ws layout (floats)
#define R_OFF   0                      // [8][21][1000]
#define TR_OFF  (NB_IMG*NCLS*SPIX)     // [8]
#define NS_OFF  (TR_OFF + NB_IMG)      // [1] norm^2
#define CNT_OFF (NS_OFF + 1)           // [1] valid count
#define CTR_OFF (CNT_OFF + 1)          // [1] trace-block completion counter
#define WS_FLOATS (CTR_OFF + 1)

__device__ __forceinline__ void fatomic_add(float* p, float v) {
    unsafeAtomicAdd(p, v);   // native ds_add_f32 / global_atomic_add_f32
}

// Scatter + (on blockIdx.y==8) the ||W||^2 and valid-count reductions.
// Protocol per iteration (all LDS ops in-order within a wave):
//   dedup(lane-local) -> claims x8 -> readback x8 -> RMW-read x8 -> winner-
//   write x8 (branchless dump-slot addressing) -> ROUND-2 claims/readback/
//   RMW for round-1 losers (~26% at KE=8) -> rare (~2%) ds_add fallback.
__global__ __launch_bounds__(512, 4) void scatter_kernel(const float* __restrict__ pred,
                                                         const int* __restrict__ seg,
                                                         const float* __restrict__ W,
                                                         float* __restrict__ Rout,
                                                         float* __restrict__ ns,
                                                         float* __restrict__ cnt) {
    if (blockIdx.y == NB_IMG) {            // -------- scalars blocks --------
        if (blockIdx.x < 128) {
            const float4* W4 = (const float4*)W;
            const int n4 = (NB_IMG * SPIX * SPIX) / 4;
            float s = 0.f;
            for (int i = blockIdx.x * 512 + threadIdx.x; i < n4; i += 128 * 512) {
                float4 v = W4[i];
                s += v.x*v.x + v.y*v.y + v.z*v.z + v.w*v.w;
            }
            #pragma unroll
            for (int off = 32; off; off >>= 1) s += __shfl_xor(s, off);
            if ((threadIdx.x & 63) == 0) fatomic_add(ns, s);
        } else {
            const int4* s4 = (const int4*)seg;
            const int n4 = (NB_IMG * PP) / 4;
            int c = 0;
            for (int i = (blockIdx.x - 128) * 512 + threadIdx.x; i < n4; i += 40 * 512) {
                int4 v = s4[i];
                c += ((unsigned)v.x < SPIX) + ((unsigned)v.y < SPIX) + ((unsigned)v.z < SPIX) + ((unsigned)v.w < SPIX);
            }
            float f = (float)c;
            #pragma unroll
            for (int off = 32; off; off >>= 1) f += __shfl_xor(f, off);
            if ((threadIdx.x & 63) == 0) fatomic_add(cnt, f);
        }
        return;
    }
    // -------- scatter blocks --------
    __shared__ float          Rw[8][1024];   // wave-private accumulators, 32 KB
    __shared__ unsigned short Mk[8][1024];   // wave-private claim markers, 16 KB
    const int b    = blockIdx.y;
    const int tid  = threadIdx.x;
    const int wave = tid >> 6;
    const unsigned short lane = (unsigned short)(tid & 63);
    const unsigned f0 = (unsigned)blockIdx.x * FWIN;
    const unsigned c0 = f0 >> 18;            // constant class row for this block
    const unsigned p0 = f0 & (PP - 1);       // window start pixel (never wraps)

    for (int i = tid; i < 8 * 1024; i += 512) ((float*)Rw)[i] = 0.f;
    __syncthreads();

    volatile float*          vR = Rw[wave];
    volatile unsigned short* vM = Mk[wave];
    float* aR = (float*)Rw[wave];

    const float* pb   = pred + (size_t)b * EPB;
    const int*   segb = seg + (size_t)b * PP + p0;

    for (int it = 0; it < FWIN / (512 * KE); ++it) {         // 8 iterations
        const int e0 = (it * 512 + tid) * KE;
        int4 sv0 = *(const int4*)(segb + e0);                // 32B/lane, coalesced
        int4 sv1 = *(const int4*)(segb + e0 + 4);
        int sA[KE]; float vA[KE];
        {   // incremental div-by-21: one magic-div per 8 elements
            unsigned fk = f0 + (unsigned)e0;
            unsigned sp = fk / 21u;
            unsigned ch = fk - sp * 21u;
            #pragma unroll
            for (int k = 0; k < KE; ++k) {
                vA[k] = pb[(ch << 18) + sp];                 // gather, L1-absorbed
                int s = (k < 4) ? (&sv0.x)[k] : (&sv1.x)[k - 4];
                sA[k] = ((unsigned)s < SPIX) ? s : DUMP;
                ch++;
                bool c21 = (ch == 21u);
                sp += c21 ? 1u : 0u;
                ch  = c21 ? 0u : ch;
            }
        }
        // lane-local dedup (merging DUMP slots is harmless)
        #pragma unroll
        for (int i = 0; i < KE - 1; ++i)
            #pragma unroll
            for (int j = i + 1; j < KE; ++j) {
                bool e = (sA[j] == sA[i]);
                vA[i] += e ? vA[j] : 0.f;
                sA[j]  = e ? DUMP  : sA[j];
            }
        // ---- round 1 ----
        #pragma unroll
        for (int k = 0; k < KE; ++k) vM[sA[k]] = lane;       // claims
        unsigned short rd[KE];
        #pragma unroll
        for (int k = 0; k < KE; ++k) rd[k] = vM[sA[k]];      // readback
        float od[KE];
        #pragma unroll
        for (int k = 0; k < KE; ++k) od[k] = vR[sA[k]];      // RMW read
        bool lose1[KE];
        #pragma unroll
        for (int k = 0; k < KE; ++k) {                       // winner write
            lose1[k] = (rd[k] != lane);
            vR[lose1[k] ? DUMP : sA[k]] = od[k] + vA[k];
        }
        // ---- round 2: rescue round-1 losers through the banked path ----
        #pragma unroll
        for (int k = 0; k < KE; ++k) vM[lose1[k] ? sA[k] : DUMP2] = lane;
        unsigned short rd2[KE];
        #pragma unroll
        for (int k = 0; k < KE; ++k) rd2[k] = vM[lose1[k] ? sA[k] : DUMP2];
        float od2[KE];
        #pragma unroll
        for (int k = 0; k < KE; ++k) od2[k] = vR[lose1[k] ? sA[k] : DUMP];
        #pragma unroll
        for (int k = 0; k < KE; ++k) {
            bool w2 = lose1[k] && (rd2[k] == lane);
            vR[w2 ? sA[k] : DUMP] = od2[k] + vA[k];
        }
        asm volatile("" ::: "memory");   // order winner writes before fallbacks
        // ---- round 3: rare fallback on the atomic pipe ----
        #pragma unroll
        for (int k = 0; k < KE; ++k) {
            if (lose1[k] && rd2[k] != lane) fatomic_add(&aR[sA[k]], vA[k]);
        }
    }
    __syncthreads();

    // merge 8 wave copies, one global atomic per bin
    float* Rb = Rout + (size_t)b * NCLS * SPIX + (size_t)c0 * SPIX;
    for (int i = tid; i < SPIX; i += 512) {
        float a = 0.f;
        #pragma unroll
        for (int w = 0; w < 8; ++w) a += Rw[w][i];
        fatomic_add(&Rb[i], a);
    }
}

// trace[b] = sum_{s,t} L[b,s,t] * sum_c R[b,c,s]*R[b,c,t]; last block finalizes.
__global__ __launch_bounds__(512) void trace_kernel(const float* __restrict__ L,
                                                    const float* __restrict__ R,
                                                    float* __restrict__ traces,
                                                    const float* __restrict__ ns,
                                                    const float* __restrict__ cnt,
                                                    unsigned* __restrict__ ctr,
                                                    float* __restrict__ out) {
    __shared__ float Rl[NCLS * SPIX];   // 84 KB
    const int b = blockIdx.y;
    const float* Rb = R + (size_t)b * NCLS * SPIX;
    for (int i = threadIdx.x; i < NCLS * SPIX; i += 512) Rl[i] = Rb[i];
    __syncthreads();

    const int wave = threadIdx.x >> 6;
    const int lane = threadIdx.x & 63;
    const float* Lb = L + (size_t)b * SPIX * SPIX;

    const int s0 = (blockIdx.x * 8 + wave) * 4;   // 32 blocks * 8 waves * 4 rows = 1024
    bool val[4];
    const float4* Lr[4];
    #pragma unroll
    for (int r = 0; r < 4; ++r) {
        int sr = s0 + r;
        val[r] = sr < SPIX;
        Lr[r] = (const float4*)(Lb + (size_t)(val[r] ? sr : (SPIX - 1)) * SPIX);
    }

    float acc[4][NCLS];
    #pragma unroll
    for (int r = 0; r < 4; ++r)
        #pragma unroll
        for (int c = 0; c < NCLS; ++c) acc[r][c] = 0.f;

    #pragma unroll
    for (int it = 0; it < 4; ++it) {
        int idx = it * 64 + lane;          // float4 index within row, 0..249
        if (idx < SPIX / 4) {
            float4 l[4];
            #pragma unroll
            for (int r = 0; r < 4; ++r)
                l[r] = val[r] ? Lr[r][idx] : make_float4(0.f, 0.f, 0.f, 0.f);
            #pragma unroll
            for (int c = 0; c < NCLS; ++c) {
                float4 rr = *(const float4*)&Rl[c * SPIX + idx * 4];
                #pragma unroll
                for (int r = 0; r < 4; ++r)
                    acc[r][c] += l[r].x * rr.x + l[r].y * rr.y + l[r].z * rr.z + l[r].w * rr.w;
            }
        }
    }

    float partial = 0.f;
    #pragma unroll
    for (int c = 0; c < NCLS; ++c)
        #pragma unroll
        for (int r = 0; r < 4; ++r)
            if (val[r]) partial += Rl[c * SPIX + s0 + r] * acc[r][c];

    #pragma unroll
    for (int off = 32; off; off >>= 1) partial += __shfl_xor(partial, off);
    if (lane == 0) fatomic_add(&traces[b], partial);

    __syncthreads();
    if (threadIdx.x == 0) {
        __threadfence();
        unsigned old = atomicAdd(ctr, 1u);
        if (old == 32u * NB_IMG - 1u) {    // last block finalizes
            __threadfence();
            float t = 0.f;
            #pragma unroll
            for (int i = 0; i < NB_IMG; ++i)
                t += __hip_atomic_load(&traces[i], __ATOMIC_RELAXED, __HIP_MEMORY_SCOPE_AGENT);
            float denom = cnt[0] + 1e-16f;
            out[0] = (2.f / sqrtf(ns[0])) * t / (denom * denom) / (float)NB_IMG;
        }
    }
}

extern "C" void kernel_launch(void* const* d_in, const int* in_sizes, int n_in,
                              void* d_out, int out_size, void* d_ws, size_t ws_size,
                              hipStream_t stream) {
    const float* pred = (const float*)d_in[0];
    const float* Wc   = (const float*)d_in[1];
    const float* Lc   = (const float*)d_in[2];
    const int*   seg  = (const int*)d_in[3];
    float* ws = (float*)d_ws;
    float* out = (float*)d_out;

    hipMemsetAsync(d_ws, 0, WS_FLOATS * sizeof(float), stream);

    scatter_kernel<<<dim3(BLKS_PER_B, NB_IMG + 1), 512, 0, stream>>>(
        pred, seg, Wc, ws + R_OFF, ws + NS_OFF, ws + CNT_OFF);

    trace_kernel<<<dim3(32, NB_IMG), 512, 0, stream>>>(
        Lc, ws + R_OFF, ws + TR_OFF, ws + NS_OFF, ws + CNT_OFF,
        (unsigned*)(ws + CTR_OFF), out);
}

// Round 8
// 182.086 us; speedup vs baseline: 1.0378x; 1.0378x over previous
//
#include <hip/hip_runtime.h>
#include <hip/hip_bf16.h>

#define SPIX 1000
#define NCLS 21
#define PP (512*512)          // pixels per image, 2^18
#define NB_IMG 8
#define EPB (NCLS*PP)         // elements per batch in pred (= 21*2^18 f-values)

// scatter geometry: contiguous 32768-wide f-window per block; 2^15 | 2^18 so
// the class row c = f>>18 is CONSTANT within a block.
#define FWIN 32768
#define BLKS_PER_B (EPB / FWIN)   // 168
#define DUMP 1000                 // garbage accumulator slot (rows sized 1024)

// ws layout (floats)
#define R_OFF   0                      // [8][21][1000]
#define TR_OFF  (NB_IMG*NCLS*SPIX)     // [8]
#define NS_OFF  (TR_OFF + NB_IMG)      // [1] norm^2
#define CNT_OFF (NS_OFF + 1)           // [1] valid count
#define CTR_OFF (CNT_OFF + 1)          // [1] trace-block completion counter
#define WS_FLOATS (CTR_OFF + 1)

__device__ __forceinline__ void fatomic_add(float* p, float v) {
    unsafeAtomicAdd(p, v);   // native ds_add_f32 / global_atomic_add_f32
}

// Scatter + (on blockIdx.y==8) the ||W||^2 and valid-count reductions.
// Protocol per iteration (all LDS ops in-order within a wave's DS FIFO):
//   dedup -> claims x4 -> readback x4 -> RMW-read x4 -> winner-write x4
//   (branchless dump-slot addressing) -> EXEC-MASKED round-2 rescue for the
//   ~13% round-1 losers -> ds_add fallback only for double-losers (~1%).
__global__ __launch_bounds__(512, 4) void scatter_kernel(const float* __restrict__ pred,
                                                         const int* __restrict__ seg,
                                                         const float* __restrict__ W,
                                                         float* __restrict__ Rout,
                                                         float* __restrict__ ns,
                                                         float* __restrict__ cnt) {
    if (blockIdx.y == NB_IMG) {            // -------- scalars blocks --------
        if (blockIdx.x < 128) {
            const float4* W4 = (const float4*)W;
            const int n4 = (NB_IMG * SPIX * SPIX) / 4;
            float s = 0.f;
            for (int i = blockIdx.x * 512 + threadIdx.x; i < n4; i += 128 * 512) {
                float4 v = W4[i];
                s += v.x*v.x + v.y*v.y + v.z*v.z + v.w*v.w;
            }
            #pragma unroll
            for (int off = 32; off; off >>= 1) s += __shfl_xor(s, off);
            if ((threadIdx.x & 63) == 0) fatomic_add(ns, s);
        } else {
            const int4* s4 = (const int4*)seg;
            const int n4 = (NB_IMG * PP) / 4;
            int c = 0;
            for (int i = (blockIdx.x - 128) * 512 + threadIdx.x; i < n4; i += 40 * 512) {
                int4 v = s4[i];
                c += ((unsigned)v.x < SPIX) + ((unsigned)v.y < SPIX) + ((unsigned)v.z < SPIX) + ((unsigned)v.w < SPIX);
            }
            float f = (float)c;
            #pragma unroll
            for (int off = 32; off; off >>= 1) f += __shfl_xor(f, off);
            if ((threadIdx.x & 63) == 0) fatomic_add(cnt, f);
        }
        return;
    }
    // -------- scatter blocks --------
    __shared__ float          Rw[8][1024];   // wave-private accumulators, 32 KB
    __shared__ unsigned short Mk[8][1024];   // wave-private claim markers, 16 KB
    const int b    = blockIdx.y;
    const int tid  = threadIdx.x;
    const int wave = tid >> 6;
    const unsigned short lane = (unsigned short)(tid & 63);
    const unsigned f0 = (unsigned)blockIdx.x * FWIN;
    const unsigned c0 = f0 >> 18;            // constant class row for this block
    const unsigned p0 = f0 & (PP - 1);       // window start pixel (never wraps)

    for (int i = tid; i < 8 * 1024; i += 512) ((float*)Rw)[i] = 0.f;
    __syncthreads();

    volatile float*          vR = Rw[wave];
    volatile unsigned short* vM = Mk[wave];
    float* aR = (float*)Rw[wave];

    const float* pb   = pred + (size_t)b * EPB;
    const int*   segb = seg + (size_t)b * PP + p0;

    for (int it = 0; it < FWIN / (512 * 4); ++it) {          // 16 iterations
        const int e0 = (it * 512 + tid) * 4;
        int4 sv = *(const int4*)(segb + e0);                 // coalesced
        const unsigned fk0 = f0 + (unsigned)e0;
        int sA[4]; float vA[4];
        #pragma unroll
        for (int k = 0; k < 4; ++k) {
            unsigned fk = fk0 + k;
            unsigned sp = fk / 21u;                          // magic-mul
            unsigned ch = fk - sp * 21u;
            vA[k] = pb[(ch << 18) + sp];                     // gather, L1-absorbed
            int s = (&sv.x)[k];
            sA[k] = ((unsigned)s < SPIX) ? s : DUMP;
        }
        // lane-local dedup: merge equal bins so a lane wins a bin at most once
        #pragma unroll
        for (int i = 0; i < 3; ++i)
            #pragma unroll
            for (int j = i + 1; j < 4; ++j) {
                bool e = (sA[j] == sA[i]) && (sA[i] != DUMP);
                vA[i] += e ? vA[j] : 0.f;
                sA[j]  = e ? DUMP  : sA[j];
            }
        // ---- round 1 (all lanes, phase-batched) ----
        #pragma unroll
        for (int k = 0; k < 4; ++k) vM[sA[k]] = lane;        // claims
        unsigned short rd[4];
        #pragma unroll
        for (int k = 0; k < 4; ++k) rd[k] = vM[sA[k]];       // readback
        float od[4];
        #pragma unroll
        for (int k = 0; k < 4; ++k) od[k] = vR[sA[k]];       // RMW read
        bool lose1[4];
        #pragma unroll
        for (int k = 0; k < 4; ++k) {                        // winner write
            lose1[k] = (rd[k] != lane);
            vR[lose1[k] ? DUMP : sA[k]] = od[k] + vA[k];
        }
        // ---- round 2: exec-masked rescue (~13% of lanes active) ----
        #pragma unroll
        for (int k = 0; k < 4; ++k) { if (lose1[k]) vM[sA[k]] = lane; }
        unsigned short rd2[4];
        #pragma unroll
        for (int k = 0; k < 4; ++k) rd2[k] = lose1[k] ? vM[sA[k]] : (unsigned short)0xffffu;
        float od2[4];
        #pragma unroll
        for (int k = 0; k < 4; ++k) od2[k] = lose1[k] ? vR[sA[k]] : 0.f;
        #pragma unroll
        for (int k = 0; k < 4; ++k) {
            if (rd2[k] == lane) vR[sA[k]] = od2[k] + vA[k];  // round-2 winners
        }
        asm volatile("" ::: "memory");   // order winner writes before fallbacks
        // ---- round 3: double-losers on the atomic pipe (~1%) ----
        #pragma unroll
        for (int k = 0; k < 4; ++k) {
            if (lose1[k] && rd2[k] != lane) fatomic_add(&aR[sA[k]], vA[k]);
        }
    }
    __syncthreads();

    // merge 8 wave copies, one global atomic per bin
    float* Rb = Rout + (size_t)b * NCLS * SPIX + (size_t)c0 * SPIX;
    for (int i = tid; i < SPIX; i += 512) {
        float a = 0.f;
        #pragma unroll
        for (int w = 0; w < 8; ++w) a += Rw[w][i];
        fatomic_add(&Rb[i], a);
    }
}

// trace[b] = sum_{s,t} L[b,s,t] * sum_c R[b,c,s]*R[b,c,t]; last block finalizes.
__global__ __launch_bounds__(512) void trace_kernel(const float* __restrict__ L,
                                                    const float* __restrict__ R,
                                                    float* __restrict__ traces,
                                                    const float* __restrict__ ns,
                                                    const float* __restrict__ cnt,
                                                    unsigned* __restrict__ ctr,
                                                    float* __restrict__ out) {
    __shared__ float Rl[NCLS * SPIX];   // 84 KB
    const int b = blockIdx.y;
    const float* Rb = R + (size_t)b * NCLS * SPIX;
    for (int i = threadIdx.x; i < NCLS * SPIX; i += 512) Rl[i] = Rb[i];
    __syncthreads();

    const int wave = threadIdx.x >> 6;
    const int lane = threadIdx.x & 63;
    const float* Lb = L + (size_t)b * SPIX * SPIX;

    const int s0 = (blockIdx.x * 8 + wave) * 4;   // 32 blocks * 8 waves * 4 rows = 1024
    bool val[4];
    const float4* Lr[4];
    #pragma unroll
    for (int r = 0; r < 4; ++r) {
        int sr = s0 + r;
        val[r] = sr < SPIX;
        Lr[r] = (const float4*)(Lb + (size_t)(val[r] ? sr : (SPIX - 1)) * SPIX);
    }

    float acc[4][NCLS];
    #pragma unroll
    for (int r = 0; r < 4; ++r)
        #pragma unroll
        for (int c = 0; c < NCLS; ++c) acc[r][c] = 0.f;

    #pragma unroll
    for (int it = 0; it < 4; ++it) {
        int idx = it * 64 + lane;          // float4 index within row, 0..249
        if (idx < SPIX / 4) {
            float4 l[4];
            #pragma unroll
            for (int r = 0; r < 4; ++r)
                l[r] = val[r] ? Lr[r][idx] : make_float4(0.f, 0.f, 0.f, 0.f);
            #pragma unroll
            for (int c = 0; c < NCLS; ++c) {
                float4 rr = *(const float4*)&Rl[c * SPIX + idx * 4];
                #pragma unroll
                for (int r = 0; r < 4; ++r)
                    acc[r][c] += l[r].x * rr.x + l[r].y * rr.y + l[r].z * rr.z + l[r].w * rr.w;
            }
        }
    }

    float partial = 0.f;
    #pragma unroll
    for (int c = 0; c < NCLS; ++c)
        #pragma unroll
        for (int r = 0; r < 4; ++r)
            if (val[r]) partial += Rl[c * SPIX + s0 + r] * acc[r][c];

    #pragma unroll
    for (int off = 32; off; off >>= 1) partial += __shfl_xor(partial, off);
    if (lane == 0) fatomic_add(&traces[b], partial);

    __syncthreads();
    if (threadIdx.x == 0) {
        __threadfence();
        unsigned old = atomicAdd(ctr, 1u);
        if (old == 32u * NB_IMG - 1u) {    // last block finalizes
            __threadfence();
            float t = 0.f;
            #pragma unroll
            for (int i = 0; i < NB_IMG; ++i)
                t += __hip_atomic_load(&traces[i], __ATOMIC_RELAXED, __HIP_MEMORY_SCOPE_AGENT);
            float denom = cnt[0] + 1e-16f;
            out[0] = (2.f / sqrtf(ns[0])) * t / (denom * denom) / (float)NB_IMG;
        }
    }
}

extern "C" void kernel_launch(void* const* d_in, const int* in_sizes, int n_in,
                              void* d_out, int out_size, void* d_ws, size_t ws_size,
                              hipStream_t stream) {
    const float* pred = (const float*)d_in[0];
    const float* Wc   = (const float*)d_in[1];
    const float* Lc   = (const float*)d_in[2];
    const int*   seg  = (const int*)d_in[3];
    float* ws = (float*)d_ws;
    float* out = (float*)d_out;

    hipMemsetAsync(d_ws, 0, WS_FLOATS * sizeof(float), stream);

    scatter_kernel<<<dim3(BLKS_PER_B, NB_IMG + 1), 512, 0, stream>>>(
        pred, seg, Wc, ws + R_OFF, ws + NS_OFF, ws + CNT_OFF);

    trace_kernel<<<dim3(32, NB_IMG), 512, 0, stream>>>(
        Lc, ws + R_OFF, ws + TR_OFF, ws + NS_OFF, ws + CNT_OFF,
        (unsigned*)(ws + CTR_OFF), out);
}

// Round 9
// 158.310 us; speedup vs baseline: 1.1937x; 1.1502x over previous
//
#include <hip/hip_runtime.h>
#include <hip/hip_bf16.h>

#define SPIX 1000
#define NCLS 21
#define PP (512*512)          // pixels per image, 2^18
#define NB_IMG 8
#define EPB (NCLS*PP)         // elements per batch in pred (= 21*2^18 f-values)

// scatter geometry: contiguous 32768-wide f-window per block; 2^15 | 2^18 so
// the class row c = f>>18 is CONSTANT within a block.
#define FWIN 32768
#define BLKS_PER_B (EPB / FWIN)   // 168
#define DUMP 1000                 // garbage accumulator slot (rows sized 1024)

// ws layout (floats)
#define R_OFF   0                      // [8][21][1000]
#define TR_OFF  (NB_IMG*NCLS*SPIX)     // [8]
#define NS_OFF  (TR_OFF + NB_IMG)      // [1] norm^2
#define CNT_OFF (NS_OFF + 1)           // [1] valid count
#define CTR_OFF (CNT_OFF + 1)          // [1] trace-block completion counter
#define WS_FLOATS (CTR_OFF + 1)

__device__ __forceinline__ void fatomic_add(float* p, float v) {
    unsafeAtomicAdd(p, v);   // native ds_add_f32 / global_atomic_add_f32
}

// Scatter + (on blockIdx.y==8) the ||W||^2 and valid-count reductions.
// Protocol per iteration (R6 structure, unchanged — each phase's LDS ops are
// in-order in the wave's DS FIFO):
//   dedup -> claims x4 -> readback x4 -> RMW-read x4 -> winner-write x4
//   (branchless dump-slot addressing) -> ds_add fallback for losers (~13%).
// u8 markers cut LDS to 40 KB -> 4 blocks/CU (2048 threads, full CU) so wait
// bubbles + fallback atomics pipeline across 32 resident waves.
__global__ __launch_bounds__(512, 8) void scatter_kernel(const float* __restrict__ pred,
                                                         const int* __restrict__ seg,
                                                         const float* __restrict__ W,
                                                         float* __restrict__ Rout,
                                                         float* __restrict__ ns,
                                                         float* __restrict__ cnt) {
    if (blockIdx.y == NB_IMG) {            // -------- scalars blocks --------
        if (blockIdx.x < 128) {
            const float4* W4 = (const float4*)W;
            const int n4 = (NB_IMG * SPIX * SPIX) / 4;
            float s = 0.f;
            for (int i = blockIdx.x * 512 + threadIdx.x; i < n4; i += 128 * 512) {
                float4 v = W4[i];
                s += v.x*v.x + v.y*v.y + v.z*v.z + v.w*v.w;
            }
            #pragma unroll
            for (int off = 32; off; off >>= 1) s += __shfl_xor(s, off);
            if ((threadIdx.x & 63) == 0) fatomic_add(ns, s);
        } else {
            const int4* s4 = (const int4*)seg;
            const int n4 = (NB_IMG * PP) / 4;
            int c = 0;
            for (int i = (blockIdx.x - 128) * 512 + threadIdx.x; i < n4; i += 40 * 512) {
                int4 v = s4[i];
                c += ((unsigned)v.x < SPIX) + ((unsigned)v.y < SPIX) + ((unsigned)v.z < SPIX) + ((unsigned)v.w < SPIX);
            }
            float f = (float)c;
            #pragma unroll
            for (int off = 32; off; off >>= 1) f += __shfl_xor(f, off);
            if ((threadIdx.x & 63) == 0) fatomic_add(cnt, f);
        }
        return;
    }
    // -------- scatter blocks --------
    __shared__ float         Rw[8][1024];   // wave-private accumulators, 32 KB
    __shared__ unsigned char Mk[8][1024];   // wave-private claim markers, 8 KB
    const int b    = blockIdx.y;
    const int tid  = threadIdx.x;
    const int wave = tid >> 6;
    const unsigned char lane = (unsigned char)(tid & 63);
    const unsigned f0 = (unsigned)blockIdx.x * FWIN;
    const unsigned c0 = f0 >> 18;            // constant class row for this block
    const unsigned p0 = f0 & (PP - 1);       // window start pixel (never wraps)

    for (int i = tid; i < 8 * 1024; i += 512) ((float*)Rw)[i] = 0.f;
    __syncthreads();

    volatile float*         vR = Rw[wave];
    volatile unsigned char* vM = Mk[wave];
    float* aR = (float*)Rw[wave];

    const float* pb   = pred + (size_t)b * EPB;
    const int*   segb = seg + (size_t)b * PP + p0;

    for (int it = 0; it < FWIN / (512 * 4); ++it) {          // 16 iterations
        const int e0 = (it * 512 + tid) * 4;
        int4 sv = *(const int4*)(segb + e0);                 // coalesced
        int sA[4]; float vA[4];
        {   // incremental div-by-21: one magic-div per 4 elements
            unsigned fk = f0 + (unsigned)e0;
            unsigned sp = fk / 21u;
            unsigned ch = fk - sp * 21u;
            #pragma unroll
            for (int k = 0; k < 4; ++k) {
                vA[k] = pb[(ch << 18) + sp];                 // gather, L1-absorbed
                int s = (&sv.x)[k];
                sA[k] = ((unsigned)s < SPIX) ? s : DUMP;
                ch++;
                bool c21 = (ch == 21u);
                sp += c21 ? 1u : 0u;
                ch  = c21 ? 0u : ch;
            }
        }
        // lane-local dedup: merge equal bins so a lane wins a bin at most once
        #pragma unroll
        for (int i = 0; i < 3; ++i)
            #pragma unroll
            for (int j = i + 1; j < 4; ++j) {
                bool e = (sA[j] == sA[i]) && (sA[i] != DUMP);
                vA[i] += e ? vA[j] : 0.f;
                sA[j]  = e ? DUMP  : sA[j];
            }
        // phase 1: claims (4 back-to-back ds_write_b8)
        #pragma unroll
        for (int k = 0; k < 4; ++k) vM[sA[k]] = lane;
        // phase 2: claim readback (4 back-to-back ds_read_u8)
        unsigned char rd[4];
        #pragma unroll
        for (int k = 0; k < 4; ++k) rd[k] = vM[sA[k]];
        // phase 3: RMW reads (unconditional; losers read harmlessly)
        float od[4];
        #pragma unroll
        for (int k = 0; k < 4; ++k) od[k] = vR[sA[k]];
        // phase 4: winner writes, branchless (losers write garbage to DUMP)
        bool lose1[4];
        #pragma unroll
        for (int k = 0; k < 4; ++k) {
            lose1[k] = (rd[k] != lane);
            vR[lose1[k] ? DUMP : sA[k]] = od[k] + vA[k];
        }
        asm volatile("" ::: "memory");   // order winner writes before fallbacks
        // phase 5: loser fallback on the atomic pipe (~13% of lanes)
        #pragma unroll
        for (int k = 0; k < 4; ++k) {
            if (lose1[k]) fatomic_add(&aR[sA[k]], vA[k]);
        }
    }
    __syncthreads();

    // merge 8 wave copies, one global atomic per bin
    float* Rb = Rout + (size_t)b * NCLS * SPIX + (size_t)c0 * SPIX;
    for (int i = tid; i < SPIX; i += 512) {
        float a = 0.f;
        #pragma unroll
        for (int w = 0; w < 8; ++w) a += Rw[w][i];
        fatomic_add(&Rb[i], a);
    }
}

// trace[b] = sum_{s,t} L[b,s,t] * sum_c R[b,c,s]*R[b,c,t]; last block finalizes.
__global__ __launch_bounds__(512) void trace_kernel(const float* __restrict__ L,
                                                    const float* __restrict__ R,
                                                    float* __restrict__ traces,
                                                    const float* __restrict__ ns,
                                                    const float* __restrict__ cnt,
                                                    unsigned* __restrict__ ctr,
                                                    float* __restrict__ out) {
    __shared__ float Rl[NCLS * SPIX];   // 84 KB
    const int b = blockIdx.y;
    const float* Rb = R + (size_t)b * NCLS * SPIX;
    for (int i = threadIdx.x; i < NCLS * SPIX; i += 512) Rl[i] = Rb[i];
    __syncthreads();

    const int wave = threadIdx.x >> 6;
    const int lane = threadIdx.x & 63;
    const float* Lb = L + (size_t)b * SPIX * SPIX;

    const int s0 = (blockIdx.x * 8 + wave) * 4;   // 32 blocks * 8 waves * 4 rows = 1024
    bool val[4];
    const float4* Lr[4];
    #pragma unroll
    for (int r = 0; r < 4; ++r) {
        int sr = s0 + r;
        val[r] = sr < SPIX;
        Lr[r] = (const float4*)(Lb + (size_t)(val[r] ? sr : (SPIX - 1)) * SPIX);
    }

    float acc[4][NCLS];
    #pragma unroll
    for (int r = 0; r < 4; ++r)
        #pragma unroll
        for (int c = 0; c < NCLS; ++c) acc[r][c] = 0.f;

    #pragma unroll
    for (int it = 0; it < 4; ++it) {
        int idx = it * 64 + lane;          // float4 index within row, 0..249
        if (idx < SPIX / 4) {
            float4 l[4];
            #pragma unroll
            for (int r = 0; r < 4; ++r)
                l[r] = val[r] ? Lr[r][idx] : make_float4(0.f, 0.f, 0.f, 0.f);
            #pragma unroll
            for (int c = 0; c < NCLS; ++c) {
                float4 rr = *(const float4*)&Rl[c * SPIX + idx * 4];
                #pragma unroll
                for (int r = 0; r < 4; ++r)
                    acc[r][c] += l[r].x * rr.x + l[r].y * rr.y + l[r].z * rr.z + l[r].w * rr.w;
            }
        }
    }

    float partial = 0.f;
    #pragma unroll
    for (int c = 0; c < NCLS; ++c)
        #pragma unroll
        for (int r = 0; r < 4; ++r)
            if (val[r]) partial += Rl[c * SPIX + s0 + r] * acc[r][c];

    #pragma unroll
    for (int off = 32; off; off >>= 1) partial += __shfl_xor(partial, off);
    if (lane == 0) fatomic_add(&traces[b], partial);

    __syncthreads();
    if (threadIdx.x == 0) {
        __threadfence();
        unsigned old = atomicAdd(ctr, 1u);
        if (old == 32u * NB_IMG - 1u) {    // last block finalizes
            __threadfence();
            float t = 0.f;
            #pragma unroll
            for (int i = 0; i < NB_IMG; ++i)
                t += __hip_atomic_load(&traces[i], __ATOMIC_RELAXED, __HIP_MEMORY_SCOPE_AGENT);
            float denom = cnt[0] + 1e-16f;
            out[0] = (2.f / sqrtf(ns[0])) * t / (denom * denom) / (float)NB_IMG;
        }
    }
}

extern "C" void kernel_launch(void* const* d_in, const int* in_sizes, int n_in,
                              void* d_out, int out_size, void* d_ws, size_t ws_size,
                              hipStream_t stream) {
    const float* pred = (const float*)d_in[0];
    const float* Wc   = (const float*)d_in[1];
    const float* Lc   = (const float*)d_in[2];
    const int*   seg  = (const int*)d_in[3];
    float* ws = (float*)d_ws;
    float* out = (float*)d_out;

    hipMemsetAsync(d_ws, 0, WS_FLOATS * sizeof(float), stream);

    scatter_kernel<<<dim3(BLKS_PER_B, NB_IMG + 1), 512, 0, stream>>>(
        pred, seg, Wc, ws + R_OFF, ws + NS_OFF, ws + CNT_OFF);

    trace_kernel<<<dim3(32, NB_IMG), 512, 0, stream>>>(
        Lc, ws + R_OFF, ws + TR_OFF, ws + NS_OFF, ws + CNT_OFF,
        (unsigned*)(ws + CTR_OFF), out);
}

// Round 10
// 157.354 us; speedup vs baseline: 1.2009x; 1.0061x over previous
//
#include <hip/hip_runtime.h>
#include <hip/hip_bf16.h>

#define SPIX 1000
#define NCLS 21
#define PP (512*512)          // pixels per image, 2^18
#define NB_IMG 8
#define EPB (NCLS*PP)         // elements per batch in pred (= 21*2^18 f-values)

// scatter geometry: contiguous 32768-wide f-window per block; 2^15 | 2^18 so
// the class row c = f>>18 is CONSTANT within a block.
#define FWIN 32768
#define BLKS_PER_B (EPB / FWIN)   // 168
#define DUMP 1000                 // garbage accumulator slot (rows sized 1024)

// ws layout (floats)
#define R_OFF   0                      // [8][21][1000]
#define TR_OFF  (NB_IMG*NCLS*SPIX)     // [8]
#define NS_OFF  (TR_OFF + NB_IMG)      // [1] norm^2
#define CNT_OFF (NS_OFF + 1)           // [1] valid count
#define CTR_OFF (CNT_OFF + 1)          // [1] trace-block completion counter
#define WS_FLOATS (CTR_OFF + 1)

__device__ __forceinline__ void fatomic_add(float* p, float v) {
    unsafeAtomicAdd(p, v);   // native ds_add_f32 / global_atomic_add_f32
}

// Scatter + (on blockIdx.y==8) the ||W||^2 and valid-count reductions.
// R9 protocol unchanged; single change vs R9: software-pipelined prefetch.
// Iteration it issues it+1's seg load + 4 pred gathers BEFORE the LDS claim
// protocol, so global latency (~800 cyc) hides under the LDS phases (~450 cyc)
// instead of serializing with them (the per-iteration "memory" clobber had
// been blocking the compiler from doing this hoist itself).
__global__ __launch_bounds__(512, 8) void scatter_kernel(const float* __restrict__ pred,
                                                         const int* __restrict__ seg,
                                                         const float* __restrict__ W,
                                                         float* __restrict__ Rout,
                                                         float* __restrict__ ns,
                                                         float* __restrict__ cnt) {
    if (blockIdx.y == NB_IMG) {            // -------- scalars blocks --------
        if (blockIdx.x < 128) {
            const float4* W4 = (const float4*)W;
            const int n4 = (NB_IMG * SPIX * SPIX) / 4;
            float s = 0.f;
            for (int i = blockIdx.x * 512 + threadIdx.x; i < n4; i += 128 * 512) {
                float4 v = W4[i];
                s += v.x*v.x + v.y*v.y + v.z*v.z + v.w*v.w;
            }
            #pragma unroll
            for (int off = 32; off; off >>= 1) s += __shfl_xor(s, off);
            if ((threadIdx.x & 63) == 0) fatomic_add(ns, s);
        } else {
            const int4* s4 = (const int4*)seg;
            const int n4 = (NB_IMG * PP) / 4;
            int c = 0;
            for (int i = (blockIdx.x - 128) * 512 + threadIdx.x; i < n4; i += 40 * 512) {
                int4 v = s4[i];
                c += ((unsigned)v.x < SPIX) + ((unsigned)v.y < SPIX) + ((unsigned)v.z < SPIX) + ((unsigned)v.w < SPIX);
            }
            float f = (float)c;
            #pragma unroll
            for (int off = 32; off; off >>= 1) f += __shfl_xor(f, off);
            if ((threadIdx.x & 63) == 0) fatomic_add(cnt, f);
        }
        return;
    }
    // -------- scatter blocks --------
    __shared__ float         Rw[8][1024];   // wave-private accumulators, 32 KB
    __shared__ unsigned char Mk[8][1024];   // wave-private claim markers, 8 KB
    const int b    = blockIdx.y;
    const int tid  = threadIdx.x;
    const int wave = tid >> 6;
    const unsigned char lane = (unsigned char)(tid & 63);
    const unsigned f0 = (unsigned)blockIdx.x * FWIN;
    const unsigned c0 = f0 >> 18;            // constant class row for this block
    const unsigned p0 = f0 & (PP - 1);       // window start pixel (never wraps)

    for (int i = tid; i < 8 * 1024; i += 512) ((float*)Rw)[i] = 0.f;
    __syncthreads();

    volatile float*         vR = Rw[wave];
    volatile unsigned char* vM = Mk[wave];
    float* aR = (float*)Rw[wave];

    const float* pb   = pred + (size_t)b * EPB;
    const int*   segb = seg + (size_t)b * PP + p0;

    // issue-next-iteration loads (seg int4 + 4 pred gathers)
#define PREF(E0, SV, VV) do {                                     \
        SV = *(const int4*)(segb + (E0));                         \
        unsigned fk = f0 + (unsigned)(E0);                        \
        unsigned sp = fk / 21u;                                   \
        unsigned ch = fk - sp * 21u;                              \
        _Pragma("unroll")                                         \
        for (int k = 0; k < 4; ++k) {                             \
            VV[k] = pb[(ch << 18) + sp];                          \
            ch++;                                                 \
            bool c21 = (ch == 21u);                               \
            sp += c21 ? 1u : 0u;                                  \
            ch  = c21 ? 0u : ch;                                  \
        }                                                         \
    } while (0)

    int4 svN; float vN[4];
    PREF(tid * 4, svN, vN);                                  // prologue: it=0

    for (int it = 0; it < FWIN / (512 * 4); ++it) {          // 16 iterations
        int4 sv = svN;
        float vA[4] = {vN[0], vN[1], vN[2], vN[3]};
        if (it + 1 < FWIN / (512 * 4)) {
            PREF(((it + 1) * 512 + tid) * 4, svN, vN);       // in flight during protocol
        }
        int sA[4];
        #pragma unroll
        for (int k = 0; k < 4; ++k) {
            int s = (&sv.x)[k];
            sA[k] = ((unsigned)s < SPIX) ? s : DUMP;
        }
        // lane-local dedup: merge equal bins so a lane wins a bin at most once
        #pragma unroll
        for (int i = 0; i < 3; ++i)
            #pragma unroll
            for (int j = i + 1; j < 4; ++j) {
                bool e = (sA[j] == sA[i]) && (sA[i] != DUMP);
                vA[i] += e ? vA[j] : 0.f;
                sA[j]  = e ? DUMP  : sA[j];
            }
        // phase 1: claims (4 back-to-back ds_write_b8)
        #pragma unroll
        for (int k = 0; k < 4; ++k) vM[sA[k]] = lane;
        // phase 2: claim readback (4 back-to-back ds_read_u8)
        unsigned char rd[4];
        #pragma unroll
        for (int k = 0; k < 4; ++k) rd[k] = vM[sA[k]];
        // phase 3: RMW reads (unconditional; losers read harmlessly)
        float od[4];
        #pragma unroll
        for (int k = 0; k < 4; ++k) od[k] = vR[sA[k]];
        // phase 4: winner writes, branchless (losers write garbage to DUMP)
        bool lose1[4];
        #pragma unroll
        for (int k = 0; k < 4; ++k) {
            lose1[k] = (rd[k] != lane);
            vR[lose1[k] ? DUMP : sA[k]] = od[k] + vA[k];
        }
        asm volatile("" ::: "memory");   // order winner writes before fallbacks
        // phase 5: loser fallback on the atomic pipe (~3%)
        #pragma unroll
        for (int k = 0; k < 4; ++k) {
            if (lose1[k]) fatomic_add(&aR[sA[k]], vA[k]);
        }
    }
#undef PREF
    __syncthreads();

    // merge 8 wave copies, one global atomic per bin
    float* Rb = Rout + (size_t)b * NCLS * SPIX + (size_t)c0 * SPIX;
    for (int i = tid; i < SPIX; i += 512) {
        float a = 0.f;
        #pragma unroll
        for (int w = 0; w < 8; ++w) a += Rw[w][i];
        fatomic_add(&Rb[i], a);
    }
}

// trace[b] = sum_{s,t} L[b,s,t] * sum_c R[b,c,s]*R[b,c,t]; last block finalizes.
__global__ __launch_bounds__(512) void trace_kernel(const float* __restrict__ L,
                                                    const float* __restrict__ R,
                                                    float* __restrict__ traces,
                                                    const float* __restrict__ ns,
                                                    const float* __restrict__ cnt,
                                                    unsigned* __restrict__ ctr,
                                                    float* __restrict__ out) {
    __shared__ float Rl[NCLS * SPIX];   // 84 KB
    const int b = blockIdx.y;
    const float* Rb = R + (size_t)b * NCLS * SPIX;
    for (int i = threadIdx.x; i < NCLS * SPIX; i += 512) Rl[i] = Rb[i];
    __syncthreads();

    const int wave = threadIdx.x >> 6;
    const int lane = threadIdx.x & 63;
    const float* Lb = L + (size_t)b * SPIX * SPIX;

    const int s0 = (blockIdx.x * 8 + wave) * 4;   // 32 blocks * 8 waves * 4 rows = 1024
    bool val[4];
    const float4* Lr[4];
    #pragma unroll
    for (int r = 0; r < 4; ++r) {
        int sr = s0 + r;
        val[r] = sr < SPIX;
        Lr[r] = (const float4*)(Lb + (size_t)(val[r] ? sr : (SPIX - 1)) * SPIX);
    }

    float acc[4][NCLS];
    #pragma unroll
    for (int r = 0; r < 4; ++r)
        #pragma unroll
        for (int c = 0; c < NCLS; ++c) acc[r][c] = 0.f;

    #pragma unroll
    for (int it = 0; it < 4; ++it) {
        int idx = it * 64 + lane;          // float4 index within row, 0..249
        if (idx < SPIX / 4) {
            float4 l[4];
            #pragma unroll
            for (int r = 0; r < 4; ++r)
                l[r] = val[r] ? Lr[r][idx] : make_float4(0.f, 0.f, 0.f, 0.f);
            #pragma unroll
            for (int c = 0; c < NCLS; ++c) {
                float4 rr = *(const float4*)&Rl[c * SPIX + idx * 4];
                #pragma unroll
                for (int r = 0; r < 4; ++r)
                    acc[r][c] += l[r].x * rr.x + l[r].y * rr.y + l[r].z * rr.z + l[r].w * rr.w;
            }
        }
    }

    float partial = 0.f;
    #pragma unroll
    for (int c = 0; c < NCLS; ++c)
        #pragma unroll
        for (int r = 0; r < 4; ++r)
            if (val[r]) partial += Rl[c * SPIX + s0 + r] * acc[r][c];

    #pragma unroll
    for (int off = 32; off; off >>= 1) partial += __shfl_xor(partial, off);
    if (lane == 0) fatomic_add(&traces[b], partial);

    __syncthreads();
    if (threadIdx.x == 0) {
        __threadfence();
        unsigned old = atomicAdd(ctr, 1u);
        if (old == 32u * NB_IMG - 1u) {    // last block finalizes
            __threadfence();
            float t = 0.f;
            #pragma unroll
            for (int i = 0; i < NB_IMG; ++i)
                t += __hip_atomic_load(&traces[i], __ATOMIC_RELAXED, __HIP_MEMORY_SCOPE_AGENT);
            float denom = cnt[0] + 1e-16f;
            out[0] = (2.f / sqrtf(ns[0])) * t / (denom * denom) / (float)NB_IMG;
        }
    }
}

extern "C" void kernel_launch(void* const* d_in, const int* in_sizes, int n_in,
                              void* d_out, int out_size, void* d_ws, size_t ws_size,
                              hipStream_t stream) {
    const float* pred = (const float*)d_in[0];
    const float* Wc   = (const float*)d_in[1];
    const float* Lc   = (const float*)d_in[2];
    const int*   seg  = (const int*)d_in[3];
    float* ws = (float*)d_ws;
    float* out = (float*)d_out;

    hipMemsetAsync(d_ws, 0, WS_FLOATS * sizeof(float), stream);

    scatter_kernel<<<dim3(BLKS_PER_B, NB_IMG + 1), 512, 0, stream>>>(
        pred, seg, Wc, ws + R_OFF, ws + NS_OFF, ws + CNT_OFF);

    trace_kernel<<<dim3(32, NB_IMG), 512, 0, stream>>>(
        Lc, ws + R_OFF, ws + TR_OFF, ws + NS_OFF, ws + CNT_OFF,
        (unsigned*)(ws + CTR_OFF), out);
}